// Round 6
// baseline (572.720 us; speedup 1.0000x reference)
//
#include <hip/hip_runtime.h>
#include <stdint.h>
#include <math.h>

// B=8, N=2048, H=1024, 2H=2048, M=B*N=16384
#define NB 8
#define NN 2048
#define HH 1024
#define K2 2048
#define MM 16384

typedef unsigned short u16;
typedef __attribute__((ext_vector_type(8))) short short8v;
typedef __attribute__((ext_vector_type(16))) float floatx16;

__device__ __forceinline__ float bf2f(u16 u) { return __uint_as_float(((unsigned)u) << 16); }
__device__ __forceinline__ u16 f2bf(float f) {
  unsigned u = __float_as_uint(f);
  unsigned r = (u + 0x7fffu + ((u >> 16) & 1u)) >> 16;
  return (u16)r;
}

__device__ __forceinline__ void async16(const void* g, void* lds) {
  __builtin_amdgcn_global_load_lds((const __attribute__((address_space(1))) void*)g,
                                   (__attribute__((address_space(3))) void*)lds,
                                   16, 0, 0);
}

// bijective XCD swizzle: grids here are all multiples of 8
__device__ __forceinline__ int xcd_swz(int bid, int nblk) {
  return (bid & 7) * (nblk >> 3) + (bid >> 3);
}

#define SBAR() __builtin_amdgcn_sched_barrier(0)

#define MFMA32(a, b, c) __builtin_amdgcn_mfma_f32_32x32x16_bf16(a, b, c, 0, 0, 0)

// ======================================================================
// 128x128 tile GEMM core, 32x32x16 MFMA (20% more FLOP/cycle than 16x16
// per m119/m06), 4 waves 2x2, 256 thr, ring-3 LDS (48 KB -> still
// 3 blocks/CU), prefetch distance 2, steady-state vmcnt(8) so staging
// HBM-miss latency (~900cy) is covered by ~2 K-tiles of compute.
// Per wave per K-tile(32): 8 ds_read_b128 + 8 MFMA. acc = 2x2 floatx16.
// LDS tile 128x32 bf16, 64B rows, 16B-chunk XOR swizzle
// phys = chunk ^ ((row>>1)&3) (0 bank conflicts, verified round 2).
// A frag: row=l&31, k=(l>>5)*8+j (family analog of verified 16x16).
// C/D: col=lane&31, row=(reg&3)+8*(reg>>2)+4*(lane>>5)  [m74/m101].
// Bt is [N][K] K-major.
// ======================================================================
__device__ __forceinline__ void gemm128_core(const u16* __restrict__ A, int lda,
                                             const u16* __restrict__ Bt, int ldb,
                                             int rowA0, int rowB0, int K,
                                             u16* sA, u16* sB, floatx16 acc[2][2]) {
  const int t = threadIdx.x;       // 0..255
  const int w = t >> 6, l = t & 63;
  const int wr = w >> 1, wc = w & 1;

#pragma unroll
  for (int mi = 0; mi < 2; mi++)
#pragma unroll
    for (int ni = 0; ni < 2; ni++) acc[mi][ni] = (floatx16)(0.f);

  // staging: wave w, ops j=0,1 cover LDS rows w*32+{0..31}; lane l -> row l>>2, chunk l&3
  // source chunk inverse-swizzled: (l&3)^((l>>3)&3)
  const int srow = l >> 2;
  const int cs = (((l & 3) ^ ((l >> 3) & 3)) << 3);
  const u16* gA0 = A + (size_t)(rowA0 + w * 32 + srow) * lda + cs;
  const u16* gA1 = A + (size_t)(rowA0 + w * 32 + 16 + srow) * lda + cs;
  const u16* gB0 = Bt + (size_t)(rowB0 + w * 32 + srow) * ldb + cs;
  const u16* gB1 = Bt + (size_t)(rowB0 + w * 32 + 16 + srow) * ldb + cs;
  char* dA = (char*)sA + w * 2048 + l * 16;   // + j*1024 + buf*8192
  char* dB = (char*)sB + w * 2048 + l * 16;

  // read side (swizzled): row = base + (l&31); chunk (kk*2 + l>>5) ^ ((row>>1)&3)
  const int l31 = l & 31;
  const int arow = (wr * 64 + l31) * 64;          // + mi*2048
  const int brow = (wc * 64 + l31) * 64;          // + ni*2048
  const int pc0 = (((l >> 5) ^ ((l >> 1) & 3)) << 4);   // kk=0 chunk byte; kk=1 = pc0^32

  const int NT = K >> 5;

#define STG128(bi, kt) { const int ko_ = (kt) << 5; const int bo_ = (bi) << 13; \
    async16(gA0 + ko_, dA + bo_); async16(gA1 + ko_, dA + bo_ + 1024);          \
    async16(gB0 + ko_, dB + bo_); async16(gB1 + ko_, dB + bo_ + 1024); }

  STG128(0, 0);
  STG128(1, 1);
  int bc = 0, bs = 2;
  for (int tt = 0; tt < NT; ++tt) {
    if (tt + 2 < NT) {
      STG128(bs, tt + 2);                                  // 12 ops in flight
      asm volatile("s_waitcnt vmcnt(8)" ::: "memory");     // tile tt complete
    } else if (tt + 1 < NT) {
      asm volatile("s_waitcnt vmcnt(4)" ::: "memory");
    } else {
      asm volatile("s_waitcnt vmcnt(0)" ::: "memory");
    }
    __builtin_amdgcn_s_barrier();          // publish tile tt

    const char* a = (const char*)sA + bc * 8192;
    const char* b = (const char*)sB + bc * 8192;
    short8v a00 = *(const short8v*)(a + arow + pc0);
    short8v a01 = *(const short8v*)(a + arow + (pc0 ^ 32));
    short8v a10 = *(const short8v*)(a + arow + 2048 + pc0);
    short8v a11 = *(const short8v*)(a + arow + 2048 + (pc0 ^ 32));
    short8v b00 = *(const short8v*)(b + brow + pc0);
    short8v b01 = *(const short8v*)(b + brow + (pc0 ^ 32));
    short8v b10 = *(const short8v*)(b + brow + 2048 + pc0);
    short8v b11 = *(const short8v*)(b + brow + 2048 + (pc0 ^ 32));
    __builtin_amdgcn_s_setprio(1);
    acc[0][0] = MFMA32(a00, b00, acc[0][0]);
    acc[0][1] = MFMA32(a00, b10, acc[0][1]);
    acc[1][0] = MFMA32(a10, b00, acc[1][0]);
    acc[1][1] = MFMA32(a10, b10, acc[1][1]);
    acc[0][0] = MFMA32(a01, b01, acc[0][0]);
    acc[0][1] = MFMA32(a01, b11, acc[0][1]);
    acc[1][0] = MFMA32(a11, b01, acc[1][0]);
    acc[1][1] = MFMA32(a11, b11, acc[1][1]);
    __builtin_amdgcn_s_setprio(0);
    SBAR();                                 // pin reads+MFMA above the seal barrier
    __builtin_amdgcn_s_barrier();           // seal reads of buf bc (stage target next iter)
    bc = (bc == 2) ? 0 : bc + 1;
    bs = (bs == 2) ? 0 : bs + 1;
  }
#undef STG128
}

// ---- X = bf16(concat(sem,temp)) AND gate = sigmoid(combined.Wg + bg), one block per row ----
__global__ void __launch_bounds__(256) k_prep_gate(const float* __restrict__ sem,
                                                   const float* __restrict__ temp,
                                                   const float* __restrict__ Wg,
                                                   const float* __restrict__ bg,
                                                   u16* __restrict__ X, float* __restrict__ gate) {
  __shared__ float red[4];
  int row = blockIdx.x;
  int t = threadIdx.x, w = t >> 6, l = t & 63;
  const float* s0 = sem + (size_t)row * 1024 + t * 4;
  const float* t0 = temp + (size_t)row * 1024 + t * 4;
  u16* xr = X + (size_t)row * 2048;
  float4 a = *(const float4*)s0;
  float4 b = *(const float4*)t0;
  ushort4 oa = { f2bf(a.x), f2bf(a.y), f2bf(a.z), f2bf(a.w) };
  ushort4 ob = { f2bf(b.x), f2bf(b.y), f2bf(b.z), f2bf(b.w) };
  *(ushort4*)(xr + t * 4) = oa;
  *(ushort4*)(xr + 1024 + t * 4) = ob;
  float4 wa = *(const float4*)(Wg + t * 4);
  float4 wb = *(const float4*)(Wg + 1024 + t * 4);
  float s = a.x * wa.x + a.y * wa.y + a.z * wa.z + a.w * wa.w
          + b.x * wb.x + b.y * wb.y + b.z * wb.z + b.w * wb.w;
#pragma unroll
  for (int off = 32; off > 0; off >>= 1) s += __shfl_xor(s, off);
  if (l == 0) red[w] = s;
  __syncthreads();
  if (t == 0) {
    float tot = red[0] + red[1] + red[2] + red[3] + bg[0];
    gate[row] = 1.f / (1.f + expf(-tot));
  }
}

// ---- Wt[n][k] = bf16(W[k][n]), W: [2048][1024] f32 ----
__global__ void __launch_bounds__(256) k_transpose_w(const float* __restrict__ W,
                                                     u16* __restrict__ Wt) {
  __shared__ float s[32][33];
  int tile = blockIdx.x;  // 64 k-tiles x 32 n-tiles
  int nt = tile & 31, kt = tile >> 5;
  int tx = threadIdx.x & 31, ty = threadIdx.x >> 5;  // ty: 0..7
  int n0 = nt << 5, k0 = kt << 5;
#pragma unroll
  for (int j = 0; j < 32; j += 8)
    s[ty + j][tx] = W[(size_t)(k0 + ty + j) * 1024 + (n0 + tx)];
  __syncthreads();
#pragma unroll
  for (int j = 0; j < 32; j += 8)
    Wt[(size_t)(n0 + ty + j) * 2048 + (k0 + tx)] = f2bf(s[tx][ty + j]);
}

// ---- fused QKV projection: X[16384][2048] @ WqkvT[3072][2048]^T ----
__global__ void __launch_bounds__(256, 3) k_proj_qkv(const u16* __restrict__ X,
                                                     const u16* __restrict__ Wt,
                                                     const float* __restrict__ bq,
                                                     const float* __restrict__ bk,
                                                     const float* __restrict__ bv,
                                                     u16* __restrict__ Qb,
                                                     u16* __restrict__ Kb,
                                                     u16* __restrict__ Vt) {
  __shared__ __align__(16) u16 sA[3 * 4096];
  __shared__ __align__(16) u16 sB[3 * 4096];
  int tile = xcd_swz(blockIdx.x, 3072);
  int bm = tile / 24, bn = tile - bm * 24;   // row-major (round-2/3 proven FETCH)
  floatx16 acc[2][2];
  gemm128_core(X, K2, Wt, K2, bm * 128, bn * 128, K2, sA, sB, acc);

  const int t = threadIdx.x, w = t >> 6, l = t & 63;
  const int wr = w >> 1, wc = w & 1;
  const int l31 = l & 31, lh = l >> 5;
  const int r0 = bm * 128 + wr * 64;
  const int c0b = (bn & 7) * 128 + wc * 64;
  const int which = bn >> 3;  // 0:Q 1:K 2:V
  if (which == 2) {
#pragma unroll
    for (int mi = 0; mi < 2; mi++)
#pragma unroll
      for (int ni = 0; ni < 2; ni++) {
        int h = c0b + ni * 32 + l31;
        float bvv = bv[h];
#pragma unroll
        for (int g = 0; g < 4; g++) {
          int rg = r0 + mi * 32 + 8 * g + 4 * lh;   // %4==0, no batch crossing in 4
          int b = rg >> 11, n = rg & 2047;
          ushort4 o = { f2bf(acc[mi][ni][4 * g + 0] + bvv), f2bf(acc[mi][ni][4 * g + 1] + bvv),
                        f2bf(acc[mi][ni][4 * g + 2] + bvv), f2bf(acc[mi][ni][4 * g + 3] + bvv) };
          *(ushort4*)&Vt[((size_t)b * 1024 + h) * 2048 + n] = o;
        }
      }
  } else {
    u16* Out = (which == 0) ? Qb : Kb;
    const float* bias = (which == 0) ? bq : bk;
#pragma unroll
    for (int mi = 0; mi < 2; mi++)
#pragma unroll
      for (int ni = 0; ni < 2; ni++) {
        int c1 = c0b + ni * 32 + l31;
        float bvv = bias[c1];
#pragma unroll
        for (int r = 0; r < 16; r++) {
          int row = r0 + mi * 32 + (r & 3) + 8 * (r >> 2) + 4 * lh;
          Out[(size_t)row * 1024 + c1] = f2bf(acc[mi][ni][r] + bvv);
        }
      }
  }
}

// ---- scores: E = exp(Q.K^T/32) bf16, row sums via atomics ----
__global__ void __launch_bounds__(256, 3) k_scores(const u16* __restrict__ Q, const u16* __restrict__ Kb,
                                                   u16* __restrict__ E, float* __restrict__ lsum) {
  __shared__ __align__(16) u16 sA[3 * 4096];
  __shared__ __align__(16) u16 sB[3 * 4096];
  int tile = xcd_swz(blockIdx.x, 2048);
  int b = tile >> 8, r = tile & 255, bm = r >> 4, bn = r & 15;
  const u16* A = Q + (size_t)b * NN * HH;
  const u16* Bt = Kb + (size_t)b * NN * HH;
  floatx16 acc[2][2];
  gemm128_core(A, HH, Bt, HH, bm * 128, bn * 128, HH, sA, sB, acc);

  u16* Eb = E + (size_t)b * NN * NN;
  float* lb = lsum + b * NN;
  const int t = threadIdx.x, w = t >> 6, l = t & 63;
  const int wr = w >> 1, wc = w & 1;
  const int l31 = l & 31, lh = l >> 5;
  const int q0 = bm * 128 + wr * 64;
  const int k0c = bn * 128 + wc * 64;
#pragma unroll
  for (int mi = 0; mi < 2; mi++)
#pragma unroll
    for (int r = 0; r < 16; r++) {
      int q = q0 + mi * 32 + (r & 3) + 8 * (r >> 2) + 4 * lh;
      float e0 = expf(acc[mi][0][r] * 0.03125f);
      float e1 = expf(acc[mi][1][r] * 0.03125f);
      Eb[(size_t)q * NN + k0c + l31] = f2bf(e0);
      Eb[(size_t)q * NN + k0c + 32 + l31] = f2bf(e1);
      float rs = e0 + e1;
      rs += __shfl_xor(rs, 1);
      rs += __shfl_xor(rs, 2);
      rs += __shfl_xor(rs, 4);
      rs += __shfl_xor(rs, 8);
      rs += __shfl_xor(rs, 16);
      if (l31 == 0) atomicAdd(&lb[q], rs);
    }
}

// ---- PV: out = (gate/l).(E @ V) + sem, f32 ----
__global__ void __launch_bounds__(256, 3) k_pv(const u16* __restrict__ E, const u16* __restrict__ Vt,
                                               const float* __restrict__ gate, const float* __restrict__ lsum,
                                               const float* __restrict__ sem, float* __restrict__ out) {
  __shared__ __align__(16) u16 sA[3 * 4096];
  __shared__ __align__(16) u16 sB[3 * 4096];
  int tile = xcd_swz(blockIdx.x, 1024);
  int b = tile >> 7, r = tile & 127, bm = r >> 3, bn = r & 7;
  const u16* A = E + (size_t)b * NN * NN;
  const u16* Bt = Vt + (size_t)b * HH * NN;
  floatx16 acc[2][2];
  gemm128_core(A, NN, Bt, NN, bm * 128, bn * 128, NN, sA, sB, acc);

  const int t = threadIdx.x, w = t >> 6, l = t & 63;
  const int wr = w >> 1, wc = w & 1;
  const int l31 = l & 31, lh = l >> 5;
  const int q0 = bm * 128 + wr * 64;
  const int h0 = bn * 128 + wc * 64;
#pragma unroll
  for (int mi = 0; mi < 2; mi++)
#pragma unroll
    for (int r = 0; r < 16; r++) {
      int q = q0 + mi * 32 + (r & 3) + 8 * (r >> 2) + 4 * lh;
      size_t gq = (size_t)b * NN + q;
      float wq = gate[gq] / lsum[gq];
      int h = h0 + l31;
      out[gq * HH + h] = acc[mi][0][r] * wq + sem[gq * HH + h];
      out[gq * HH + h + 32] = acc[mi][1][r] * wq + sem[gq * HH + h + 32];
    }
}

// ---- column mean: cm[b][k] = (1/N) * sum_q (gate/l)_q * E[b][q][k] ----
__global__ void __launch_bounds__(256) k_colmean(const u16* __restrict__ E, const float* __restrict__ gate,
                                                 const float* __restrict__ lsum, float* __restrict__ cm) {
  __shared__ float wsh[256];
  int bid = blockIdx.x;           // 8 b x 8 kslice x 8 qchunk
  int b = bid >> 6, rest = bid & 63;
  int ks = rest >> 3, qc = rest & 7;
  int t = threadIdx.x;
  {
    size_t gq = (size_t)b * NN + qc * 256 + t;
    wsh[t] = gate[gq] / lsum[gq];
  }
  __syncthreads();
  int k = ks * 256 + t;
  const u16* Eb = E + ((size_t)b * NN + (size_t)qc * 256) * NN + k;
  float s = 0.f;
  for (int q = 0; q < 256; q++) s += wsh[q] * bf2f(Eb[(size_t)q * NN]);
  atomicAdd(&cm[b * NN + k], s * (1.f / 2048.f));
}

extern "C" void kernel_launch(void* const* d_in, const int* in_sizes, int n_in,
                              void* d_out, int out_size, void* d_ws, size_t ws_size,
                              hipStream_t stream) {
  const float* sem  = (const float*)d_in[0];
  const float* temp = (const float*)d_in[1];
  const float* Wq   = (const float*)d_in[2];
  const float* bq   = (const float*)d_in[3];
  const float* Wk   = (const float*)d_in[4];
  const float* bk   = (const float*)d_in[5];
  const float* Wv   = (const float*)d_in[6];
  const float* bv   = (const float*)d_in[7];
  const float* Wg   = (const float*)d_in[8];
  const float* bg   = (const float*)d_in[9];
  float* out = (float*)d_out;

  char* ws = (char*)d_ws;
  u16* X      = (u16*)ws;                      // 67,108,864 B (reused as E later)
  u16* E      = X;
  u16* WqkvT  = (u16*)(ws + 67108864);         // 3072x2048 bf16 = 12,582,912 B
  u16* Qb     = (u16*)(ws + 79691776);         // 33,554,432 B each
  u16* Kb     = (u16*)(ws + 113246208);
  u16* Vt     = (u16*)(ws + 146800640);
  float* gate = (float*)(ws + 180355072);      // 65,536 B
  float* lsum = (float*)(ws + 180420608);      // 65,536 B

  hipMemsetAsync(lsum, 0, 65536, stream);
  hipMemsetAsync(out + 16777216, 0, 65536, stream);  // colmean region of d_out

  k_prep_gate<<<16384, 256, 0, stream>>>(sem, temp, Wg, bg, X, gate);
  k_transpose_w<<<2048, 256, 0, stream>>>(Wq, WqkvT);
  k_transpose_w<<<2048, 256, 0, stream>>>(Wk, WqkvT + (size_t)1024 * 2048);
  k_transpose_w<<<2048, 256, 0, stream>>>(Wv, WqkvT + (size_t)2048 * 2048);
  k_proj_qkv<<<3072, 256, 0, stream>>>(X, WqkvT, bq, bk, bv, Qb, Kb, Vt);
  k_scores<<<2048, 256, 0, stream>>>(Qb, Kb, E, lsum);   // overwrites X with E (X dead now)
  k_pv<<<1024, 256, 0, stream>>>(E, Vt, gate, lsum, sem, out);
  k_colmean<<<512, 256, 0, stream>>>(E, gate, lsum, out + 16777216);
}

// Round 7
// 505.105 us; speedup vs baseline: 1.1339x; 1.1339x over previous
//
#include <hip/hip_runtime.h>
#include <stdint.h>
#include <math.h>

// B=8, N=2048, H=1024, 2H=2048, M=B*N=16384
#define NB 8
#define NN 2048
#define HH 1024
#define K2 2048
#define MM 16384

typedef unsigned short u16;
typedef __attribute__((ext_vector_type(8))) short short8v;
typedef __attribute__((ext_vector_type(4))) float floatx4;

__device__ __forceinline__ float bf2f(u16 u) { return __uint_as_float(((unsigned)u) << 16); }
__device__ __forceinline__ u16 f2bf(float f) {
  unsigned u = __float_as_uint(f);
  unsigned r = (u + 0x7fffu + ((u >> 16) & 1u)) >> 16;
  return (u16)r;
}

__device__ __forceinline__ void async16(const void* g, void* lds) {
  __builtin_amdgcn_global_load_lds((const __attribute__((address_space(1))) void*)g,
                                   (__attribute__((address_space(3))) void*)lds,
                                   16, 0, 0);
}

// bijective XCD swizzle: grids here are all multiples of 8
__device__ __forceinline__ int xcd_swz(int bid, int nblk) {
  return (bid & 7) * (nblk >> 3) + (bid >> 3);
}

#define SBAR() __builtin_amdgcn_sched_barrier(0)

// ======================================================================
// 128x128 tile GEMM core (round-5 proven: 502us config).
// 16x16x32 MFMA, 4 waves 2x2, 256 thr, double-buffered 32KB LDS,
// counted vmcnt(4): next tile's 4 loads stay in flight across BOTH raw
// s_barriers. 3+ blocks/CU (60 VGPR + 64 AGPR). LDS tile 128x32 bf16,
// 64B rows, 16B-chunk XOR swizzle phys = chunk ^ ((row>>1)&3):
// 0 bank conflicts MEASURED with this 16-row x 4-chunk fragment pattern
// (round 2/5). NOTE round 6: the 32x32 fragment pattern (32 rows x same
// chunk) 4-way conflicts under this swizzle - do not swap MFMA shape
// without re-deriving the swizzle. Bt is [N][K] K-major.
// ======================================================================
__device__ __forceinline__ void gemm128_core(const u16* __restrict__ A, int lda,
                                             const u16* __restrict__ Bt, int ldb,
                                             int rowA0, int rowB0, int K,
                                             u16* sA, u16* sB, floatx4 acc[4][4]) {
  const int t = threadIdx.x;       // 0..255
  const int w = t >> 6, l = t & 63;
  const int wr = w >> 1, wc = w & 1;

#pragma unroll
  for (int mi = 0; mi < 4; mi++)
#pragma unroll
    for (int ni = 0; ni < 4; ni++) { floatx4 z = {0.f,0.f,0.f,0.f}; acc[mi][ni] = z; }

  // staging: wave w, load j covers LDS rows w*32+j*16 .. +15; lane l -> (row l>>2, chunk l&3)
  // source chunk inverse-swizzled: (l&3)^((l>>3)&3)
  const int srow = l >> 2;
  const int cs = (((l & 3) ^ ((l >> 3) & 3)) << 3);
  const u16* gA0 = A + (size_t)(rowA0 + w * 32 + srow) * lda + cs;
  const u16* gA1 = A + (size_t)(rowA0 + w * 32 + 16 + srow) * lda + cs;
  const u16* gB0 = Bt + (size_t)(rowB0 + w * 32 + srow) * ldb + cs;
  const u16* gB1 = Bt + (size_t)(rowB0 + w * 32 + 16 + srow) * ldb + cs;
  char* dA = (char*)sA + w * 2048 + l * 16;   // + j*1024 + buf*8192
  char* dB = (char*)sB + w * 2048 + l * 16;

  // read side (swizzled): global chunk (l>>4) of row fr -> phys (l>>4)^((fr>>1)&3)
  const int fr = l & 15;
  const int ch = (((l >> 4) ^ ((fr >> 1) & 3)) << 4);
  const int abase = wr * 4096 + fr * 64 + ch;   // + mi*1024 (16 rows)
  const int bbase = wc * 4096 + fr * 64 + ch;   // + ni*1024

  const int NT = K >> 5;

#define STG128(bi, kt) { const int ko_ = (kt) << 5; const int bo_ = (bi) << 13; \
    async16(gA0 + ko_, dA + bo_); async16(gA1 + ko_, dA + bo_ + 1024);          \
    async16(gB0 + ko_, dB + bo_); async16(gB1 + ko_, dB + bo_ + 1024); }

  STG128(0, 0);
  for (int tt = 0; tt < NT; ++tt) {
    const int bc = tt & 1;
    if (tt + 1 < NT) {
      STG128(bc ^ 1, tt + 1);
      asm volatile("s_waitcnt vmcnt(4)" ::: "memory");  // tile tt done; tt+1 stays in flight
    } else {
      asm volatile("s_waitcnt vmcnt(0)" ::: "memory");
    }
    __builtin_amdgcn_s_barrier();          // publish tile tt

    const char* a = (const char*)sA + (bc << 13);
    const char* b = (const char*)sB + (bc << 13);
    short8v af[4], bf[4];
#pragma unroll
    for (int mi = 0; mi < 4; mi++) af[mi] = *(const short8v*)(a + abase + mi * 1024);
#pragma unroll
    for (int ni = 0; ni < 4; ni++) bf[ni] = *(const short8v*)(b + bbase + ni * 1024);
    __builtin_amdgcn_s_setprio(1);
#pragma unroll
    for (int mi = 0; mi < 4; mi++)
#pragma unroll
      for (int ni = 0; ni < 4; ni++)
        acc[mi][ni] = __builtin_amdgcn_mfma_f32_16x16x32_bf16(af[mi], bf[ni], acc[mi][ni], 0, 0, 0);
    __builtin_amdgcn_s_setprio(0);
    SBAR();                                 // pin reads+MFMA above the seal barrier
    __builtin_amdgcn_s_barrier();           // seal reads of buf bc before next STG overwrites
  }
#undef STG128
}

// ---- X = bf16(concat(sem,temp)) AND gate = sigmoid(combined.Wg + bg) ----
// 8 rows per block: Wg hoisted to registers once (was 8KB re-read per row).
__global__ void __launch_bounds__(256) k_prep_gate(const float* __restrict__ sem,
                                                   const float* __restrict__ temp,
                                                   const float* __restrict__ Wg,
                                                   const float* __restrict__ bg,
                                                   u16* __restrict__ X, float* __restrict__ gate) {
  __shared__ float red[4];
  int t = threadIdx.x, w = t >> 6, l = t & 63;
  float4 wa = *(const float4*)(Wg + t * 4);
  float4 wb = *(const float4*)(Wg + 1024 + t * 4);
  float bgv = bg[0];
  int row0 = blockIdx.x * 8;
  for (int rr = 0; rr < 8; rr++) {
    int row = row0 + rr;
    const float* s0 = sem + (size_t)row * 1024 + t * 4;
    const float* t0 = temp + (size_t)row * 1024 + t * 4;
    u16* xr = X + (size_t)row * 2048;
    float4 a = *(const float4*)s0;
    float4 b = *(const float4*)t0;
    ushort4 oa = { f2bf(a.x), f2bf(a.y), f2bf(a.z), f2bf(a.w) };
    ushort4 ob = { f2bf(b.x), f2bf(b.y), f2bf(b.z), f2bf(b.w) };
    *(ushort4*)(xr + t * 4) = oa;
    *(ushort4*)(xr + 1024 + t * 4) = ob;
    float s = a.x * wa.x + a.y * wa.y + a.z * wa.z + a.w * wa.w
            + b.x * wb.x + b.y * wb.y + b.z * wb.z + b.w * wb.w;
#pragma unroll
    for (int off = 32; off > 0; off >>= 1) s += __shfl_xor(s, off);
    if (l == 0) red[w] = s;
    __syncthreads();
    if (t == 0) {
      float tot = red[0] + red[1] + red[2] + red[3] + bgv;
      gate[row] = 1.f / (1.f + expf(-tot));
    }
    __syncthreads();
  }
}

// ---- Wt[n][k] = bf16(W[k][n]), W: [2048][1024] f32 ----
__global__ void __launch_bounds__(256) k_transpose_w(const float* __restrict__ W,
                                                     u16* __restrict__ Wt) {
  __shared__ float s[32][33];
  int tile = blockIdx.x;  // 64 k-tiles x 32 n-tiles
  int nt = tile & 31, kt = tile >> 5;
  int tx = threadIdx.x & 31, ty = threadIdx.x >> 5;  // ty: 0..7
  int n0 = nt << 5, k0 = kt << 5;
#pragma unroll
  for (int j = 0; j < 32; j += 8)
    s[ty + j][tx] = W[(size_t)(k0 + ty + j) * 1024 + (n0 + tx)];
  __syncthreads();
#pragma unroll
  for (int j = 0; j < 32; j += 8)
    Wt[(size_t)(n0 + ty + j) * 2048 + (k0 + tx)] = f2bf(s[tx][ty + j]);
}

// ---- fused QKV projection: X[16384][2048] @ WqkvT[3072][2048]^T ----
__global__ void __launch_bounds__(256, 3) k_proj_qkv(const u16* __restrict__ X,
                                                     const u16* __restrict__ Wt,
                                                     const float* __restrict__ bq,
                                                     const float* __restrict__ bk,
                                                     const float* __restrict__ bv,
                                                     u16* __restrict__ Qb,
                                                     u16* __restrict__ Kb,
                                                     u16* __restrict__ Vt) {
  __shared__ __align__(16) u16 sA[2 * 4096];
  __shared__ __align__(16) u16 sB[2 * 4096];
  int tile = xcd_swz(blockIdx.x, 3072);
  int bm = tile / 24, bn = tile - bm * 24;   // row-major
  floatx4 acc[4][4];
  gemm128_core(X, K2, Wt, K2, bm * 128, bn * 128, K2, sA, sB, acc);

  const int t = threadIdx.x, w = t >> 6, l = t & 63;
  const int wr = w >> 1, wc = w & 1;
  const int r0 = bm * 128 + wr * 64 + ((l >> 4) << 2);
  const int c0 = (bn & 7) * 128 + wc * 64 + (l & 15);
  const int which = bn >> 3;  // 0:Q 1:K 2:V
  if (which == 2) {
#pragma unroll
    for (int ni = 0; ni < 4; ni++) {
      int h = c0 + ni * 16;
      float bvv = bv[h];
#pragma unroll
      for (int mi = 0; mi < 4; mi++) {
        int rg = r0 + mi * 16;                 // %4==0, no batch crossing
        int b = rg >> 11, n = rg & 2047;
        ushort4 o = { f2bf(acc[mi][ni][0] + bvv), f2bf(acc[mi][ni][1] + bvv),
                      f2bf(acc[mi][ni][2] + bvv), f2bf(acc[mi][ni][3] + bvv) };
        *(ushort4*)&Vt[((size_t)b * 1024 + h) * 2048 + n] = o;
      }
    }
  } else {
    u16* Out = (which == 0) ? Qb : Kb;
    const float* bias = (which == 0) ? bq : bk;
#pragma unroll
    for (int ni = 0; ni < 4; ni++) {
      int c1 = c0 + ni * 16;
      float bvv = bias[c1];
#pragma unroll
      for (int mi = 0; mi < 4; mi++)
#pragma unroll
        for (int i = 0; i < 4; i++)
          Out[(size_t)(r0 + mi * 16 + i) * 1024 + c1] = f2bf(acc[mi][ni][i] + bvv);
    }
  }
}

// ---- scores: E = exp(Q.K^T/32) bf16, row sums via atomics ----
__global__ void __launch_bounds__(256, 3) k_scores(const u16* __restrict__ Q, const u16* __restrict__ Kb,
                                                   u16* __restrict__ E, float* __restrict__ lsum) {
  __shared__ __align__(16) u16 sA[2 * 4096];
  __shared__ __align__(16) u16 sB[2 * 4096];
  int tile = xcd_swz(blockIdx.x, 2048);
  int b = tile >> 8, r = tile & 255, bm = r >> 4, bn = r & 15;
  const u16* A = Q + (size_t)b * NN * HH;
  const u16* Bt = Kb + (size_t)b * NN * HH;
  floatx4 acc[4][4];
  gemm128_core(A, HH, Bt, HH, bm * 128, bn * 128, HH, sA, sB, acc);

  u16* Eb = E + (size_t)b * NN * NN;
  float* lb = lsum + b * NN;
  const int t = threadIdx.x, w = t >> 6, l = t & 63;
  const int wr = w >> 1, wc = w & 1;
  const int q0 = bm * 128 + wr * 64 + ((l >> 4) << 2);
  const int k0c = bn * 128 + wc * 64 + (l & 15);
#pragma unroll
  for (int mi = 0; mi < 4; mi++)
#pragma unroll
    for (int i = 0; i < 4; i++) {
      int q = q0 + mi * 16 + i;
      float rs = 0.f;
#pragma unroll
      for (int ni = 0; ni < 4; ni++) {
        float e = expf(acc[mi][ni][i] * 0.03125f);
        Eb[(size_t)q * NN + k0c + ni * 16] = f2bf(e);
        rs += e;
      }
      rs += __shfl_xor(rs, 1);
      rs += __shfl_xor(rs, 2);
      rs += __shfl_xor(rs, 4);
      rs += __shfl_xor(rs, 8);
      if ((l & 15) == 0) atomicAdd(&lb[q], rs);
    }
}

// ---- PV: out = (gate/l).(E @ V) + sem, f32 ----
__global__ void __launch_bounds__(256, 3) k_pv(const u16* __restrict__ E, const u16* __restrict__ Vt,
                                               const float* __restrict__ gate, const float* __restrict__ lsum,
                                               const float* __restrict__ sem, float* __restrict__ out) {
  __shared__ __align__(16) u16 sA[2 * 4096];
  __shared__ __align__(16) u16 sB[2 * 4096];
  int tile = xcd_swz(blockIdx.x, 1024);
  int b = tile >> 7, r = tile & 127, bm = r >> 3, bn = r & 7;
  const u16* A = E + (size_t)b * NN * NN;
  const u16* Bt = Vt + (size_t)b * HH * NN;
  floatx4 acc[4][4];
  gemm128_core(A, NN, Bt, NN, bm * 128, bn * 128, NN, sA, sB, acc);

  const int t = threadIdx.x, w = t >> 6, l = t & 63;
  const int wr = w >> 1, wc = w & 1;
  const int q0 = bm * 128 + wr * 64 + ((l >> 4) << 2);
  const int h0 = bn * 128 + wc * 64 + (l & 15);
#pragma unroll
  for (int mi = 0; mi < 4; mi++)
#pragma unroll
    for (int i = 0; i < 4; i++) {
      int q = q0 + mi * 16 + i;
      size_t gq = (size_t)b * NN + q;
      float wq = gate[gq] / lsum[gq];
#pragma unroll
      for (int ni = 0; ni < 4; ni++) {
        int h = h0 + ni * 16;
        out[gq * HH + h] = acc[mi][ni][i] * wq + sem[gq * HH + h];
      }
    }
}

// ---- column mean (coalesced): cm[b][k] = (1/N) sum_q (gate/l)_q E[b][q][k] ----
// block = (b, kslice of 512, qchunk of 256); thread owns 2 k-slots in regs;
// 256 coalesced row reads (ushort2/lane), then 2 atomicAdds.
__global__ void __launch_bounds__(256) k_colmean(const u16* __restrict__ E, const float* __restrict__ gate,
                                                 const float* __restrict__ lsum, float* __restrict__ cm) {
  __shared__ float wsh[256];
  int bid = blockIdx.x;           // 8 b x 4 kslice x 8 qchunk
  int b = bid >> 5, rest = bid & 31;
  int ks = rest >> 3, qc = rest & 7;
  int t = threadIdx.x;
  {
    size_t gq = (size_t)b * NN + qc * 256 + t;
    wsh[t] = gate[gq] / lsum[gq];
  }
  __syncthreads();
  const u16* Eb = E + ((size_t)b * NN + (size_t)qc * 256) * NN + ks * 512 + 2 * t;
  float s0 = 0.f, s1 = 0.f;
#pragma unroll 4
  for (int q = 0; q < 256; q++) {
    unsigned v = *(const unsigned*)(Eb + (size_t)q * NN);
    float wq = wsh[q];
    s0 += wq * __uint_as_float(v << 16);
    s1 += wq * __uint_as_float(v & 0xffff0000u);
  }
  float* c = cm + b * NN + ks * 512 + 2 * t;
  atomicAdd(c, s0 * (1.f / 2048.f));
  atomicAdd(c + 1, s1 * (1.f / 2048.f));
}

extern "C" void kernel_launch(void* const* d_in, const int* in_sizes, int n_in,
                              void* d_out, int out_size, void* d_ws, size_t ws_size,
                              hipStream_t stream) {
  const float* sem  = (const float*)d_in[0];
  const float* temp = (const float*)d_in[1];
  const float* Wq   = (const float*)d_in[2];
  const float* bq   = (const float*)d_in[3];
  const float* Wk   = (const float*)d_in[4];
  const float* bk   = (const float*)d_in[5];
  const float* Wv   = (const float*)d_in[6];
  const float* bv   = (const float*)d_in[7];
  const float* Wg   = (const float*)d_in[8];
  const float* bg   = (const float*)d_in[9];
  float* out = (float*)d_out;

  char* ws = (char*)d_ws;
  u16* X      = (u16*)ws;                      // 67,108,864 B (reused as E later)
  u16* E      = X;
  u16* WqkvT  = (u16*)(ws + 67108864);         // 3072x2048 bf16 = 12,582,912 B
  u16* Qb     = (u16*)(ws + 79691776);         // 33,554,432 B each
  u16* Kb     = (u16*)(ws + 113246208);
  u16* Vt     = (u16*)(ws + 146800640);
  float* gate = (float*)(ws + 180355072);      // 65,536 B
  float* lsum = (float*)(ws + 180420608);      // 65,536 B

  hipMemsetAsync(lsum, 0, 65536, stream);
  hipMemsetAsync(out + 16777216, 0, 65536, stream);  // colmean region of d_out

  k_prep_gate<<<2048, 256, 0, stream>>>(sem, temp, Wg, bg, X, gate);
  k_transpose_w<<<2048, 256, 0, stream>>>(Wq, WqkvT);
  k_transpose_w<<<2048, 256, 0, stream>>>(Wk, WqkvT + (size_t)1024 * 2048);
  k_transpose_w<<<2048, 256, 0, stream>>>(Wv, WqkvT + (size_t)2048 * 2048);
  k_proj_qkv<<<3072, 256, 0, stream>>>(X, WqkvT, bq, bk, bv, Qb, Kb, Vt);
  k_scores<<<2048, 256, 0, stream>>>(Qb, Kb, E, lsum);   // overwrites X with E (X dead now)
  k_pv<<<1024, 256, 0, stream>>>(E, Vt, gate, lsum, sem, out);
  k_colmean<<<256, 256, 0, stream>>>(E, gate, lsum, out + 16777216);
}

// Round 8
// 501.965 us; speedup vs baseline: 1.1410x; 1.0063x over previous
//
#include <hip/hip_runtime.h>
#include <stdint.h>
#include <math.h>

// B=8, N=2048, H=1024, 2H=2048, M=B*N=16384
#define NB 8
#define NN 2048
#define HH 1024
#define K2 2048
#define MM 16384

typedef unsigned short u16;
typedef __attribute__((ext_vector_type(8))) short short8v;
typedef __attribute__((ext_vector_type(4))) float floatx4;

__device__ __forceinline__ float bf2f(u16 u) { return __uint_as_float(((unsigned)u) << 16); }
__device__ __forceinline__ u16 f2bf(float f) {
  unsigned u = __float_as_uint(f);
  unsigned r = (u + 0x7fffu + ((u >> 16) & 1u)) >> 16;
  return (u16)r;
}

__device__ __forceinline__ void async16(const void* g, void* lds) {
  __builtin_amdgcn_global_load_lds((const __attribute__((address_space(1))) void*)g,
                                   (__attribute__((address_space(3))) void*)lds,
                                   16, 0, 0);
}

// bijective XCD swizzle: grids here are all multiples of 8
__device__ __forceinline__ int xcd_swz(int bid, int nblk) {
  return (bid & 7) * (nblk >> 3) + (bid >> 3);
}

#define SBAR() __builtin_amdgcn_sched_barrier(0)

// ======================================================================
// 128x128 tile GEMM core (round-5 proven config, 786 TF on proj).
// 16x16x32 MFMA, 4 waves 2x2, 256 thr, double-buffered 32KB LDS,
// counted vmcnt(4). NOW at __launch_bounds__(256,4): 60 VGPR + 64 AGPR
// = 124 unified regs <= 128 -> 4 waves/SIMD -> 4 INDEPENDENT blocks/CU
// (LDS 4x32KB=128<=160). Cross-block overlap fills barrier stalls (m114).
// LDS tile 128x32 bf16, 64B rows, 16B-chunk XOR swizzle
// phys = chunk ^ ((row>>1)&3): 0 bank conflicts measured with the
// 16-row x 4-chunk fragment pattern (rounds 2/5/7). Do NOT change MFMA
// shape without re-deriving the swizzle (round-6 lesson).
// Bt is [N][K] K-major.
// ======================================================================
__device__ __forceinline__ void gemm128_core(const u16* __restrict__ A, int lda,
                                             const u16* __restrict__ Bt, int ldb,
                                             int rowA0, int rowB0, int K,
                                             u16* sA, u16* sB, floatx4 acc[4][4]) {
  const int t = threadIdx.x;       // 0..255
  const int w = t >> 6, l = t & 63;
  const int wr = w >> 1, wc = w & 1;

#pragma unroll
  for (int mi = 0; mi < 4; mi++)
#pragma unroll
    for (int ni = 0; ni < 4; ni++) { floatx4 z = {0.f,0.f,0.f,0.f}; acc[mi][ni] = z; }

  // staging: wave w, load j covers LDS rows w*32+j*16 .. +15; lane l -> (row l>>2, chunk l&3)
  // source chunk inverse-swizzled: (l&3)^((l>>3)&3)
  const int srow = l >> 2;
  const int cs = (((l & 3) ^ ((l >> 3) & 3)) << 3);
  const u16* gA0 = A + (size_t)(rowA0 + w * 32 + srow) * lda + cs;
  const u16* gA1 = A + (size_t)(rowA0 + w * 32 + 16 + srow) * lda + cs;
  const u16* gB0 = Bt + (size_t)(rowB0 + w * 32 + srow) * ldb + cs;
  const u16* gB1 = Bt + (size_t)(rowB0 + w * 32 + 16 + srow) * ldb + cs;
  char* dA = (char*)sA + w * 2048 + l * 16;   // + j*1024 + buf*8192
  char* dB = (char*)sB + w * 2048 + l * 16;

  // read side (swizzled): global chunk (l>>4) of row fr -> phys (l>>4)^((fr>>1)&3)
  const int fr = l & 15;
  const int ch = (((l >> 4) ^ ((fr >> 1) & 3)) << 4);
  const int abase = wr * 4096 + fr * 64 + ch;   // + mi*1024 (16 rows)
  const int bbase = wc * 4096 + fr * 64 + ch;   // + ni*1024

  const int NT = K >> 5;

#define STG128(bi, kt) { const int ko_ = (kt) << 5; const int bo_ = (bi) << 13; \
    async16(gA0 + ko_, dA + bo_); async16(gA1 + ko_, dA + bo_ + 1024);          \
    async16(gB0 + ko_, dB + bo_); async16(gB1 + ko_, dB + bo_ + 1024); }

  STG128(0, 0);
  for (int tt = 0; tt < NT; ++tt) {
    const int bc = tt & 1;
    if (tt + 1 < NT) {
      STG128(bc ^ 1, tt + 1);
      asm volatile("s_waitcnt vmcnt(4)" ::: "memory");  // tile tt done; tt+1 stays in flight
    } else {
      asm volatile("s_waitcnt vmcnt(0)" ::: "memory");
    }
    __builtin_amdgcn_s_barrier();          // publish tile tt

    const char* a = (const char*)sA + (bc << 13);
    const char* b = (const char*)sB + (bc << 13);
    short8v af[4], bf[4];
#pragma unroll
    for (int mi = 0; mi < 4; mi++) af[mi] = *(const short8v*)(a + abase + mi * 1024);
#pragma unroll
    for (int ni = 0; ni < 4; ni++) bf[ni] = *(const short8v*)(b + bbase + ni * 1024);
    __builtin_amdgcn_s_setprio(1);
#pragma unroll
    for (int mi = 0; mi < 4; mi++)
#pragma unroll
      for (int ni = 0; ni < 4; ni++)
        acc[mi][ni] = __builtin_amdgcn_mfma_f32_16x16x32_bf16(af[mi], bf[ni], acc[mi][ni], 0, 0, 0);
    __builtin_amdgcn_s_setprio(0);
    SBAR();                                 // pin reads+MFMA above the seal barrier
    __builtin_amdgcn_s_barrier();           // seal reads of buf bc before next STG overwrites
  }
#undef STG128
}

// ---- X = bf16(concat(sem,temp)) AND gate = sigmoid(combined.Wg + bg) ----
// 8 rows per block: Wg hoisted to registers once.
__global__ void __launch_bounds__(256) k_prep_gate(const float* __restrict__ sem,
                                                   const float* __restrict__ temp,
                                                   const float* __restrict__ Wg,
                                                   const float* __restrict__ bg,
                                                   u16* __restrict__ X, float* __restrict__ gate) {
  __shared__ float red[4];
  int t = threadIdx.x, w = t >> 6, l = t & 63;
  float4 wa = *(const float4*)(Wg + t * 4);
  float4 wb = *(const float4*)(Wg + 1024 + t * 4);
  float bgv = bg[0];
  int row0 = blockIdx.x * 8;
  for (int rr = 0; rr < 8; rr++) {
    int row = row0 + rr;
    const float* s0 = sem + (size_t)row * 1024 + t * 4;
    const float* t0 = temp + (size_t)row * 1024 + t * 4;
    u16* xr = X + (size_t)row * 2048;
    float4 a = *(const float4*)s0;
    float4 b = *(const float4*)t0;
    ushort4 oa = { f2bf(a.x), f2bf(a.y), f2bf(a.z), f2bf(a.w) };
    ushort4 ob = { f2bf(b.x), f2bf(b.y), f2bf(b.z), f2bf(b.w) };
    *(ushort4*)(xr + t * 4) = oa;
    *(ushort4*)(xr + 1024 + t * 4) = ob;
    float s = a.x * wa.x + a.y * wa.y + a.z * wa.z + a.w * wa.w
            + b.x * wb.x + b.y * wb.y + b.z * wb.z + b.w * wb.w;
#pragma unroll
    for (int off = 32; off > 0; off >>= 1) s += __shfl_xor(s, off);
    if (l == 0) red[w] = s;
    __syncthreads();
    if (t == 0) {
      float tot = red[0] + red[1] + red[2] + red[3] + bgv;
      gate[row] = 1.f / (1.f + expf(-tot));
    }
    __syncthreads();
  }
}

// ---- WqkvT[n][k] = bf16(W[k][n]) for all three W in one launch ----
__global__ void __launch_bounds__(256) k_transpose_w3(const float* __restrict__ Wq,
                                                      const float* __restrict__ Wk,
                                                      const float* __restrict__ Wv,
                                                      u16* __restrict__ Wt) {
  __shared__ float s[32][33];
  int tile = blockIdx.x;          // 3 x (64 k-tiles x 32 n-tiles)
  int which = tile >> 11; tile &= 2047;
  const float* W = which == 0 ? Wq : which == 1 ? Wk : Wv;
  u16* dst = Wt + (size_t)which * 1024 * 2048;
  int nt = tile & 31, kt = tile >> 5;
  int tx = threadIdx.x & 31, ty = threadIdx.x >> 5;  // ty: 0..7
  int n0 = nt << 5, k0 = kt << 5;
#pragma unroll
  for (int j = 0; j < 32; j += 8)
    s[ty + j][tx] = W[(size_t)(k0 + ty + j) * 1024 + (n0 + tx)];
  __syncthreads();
#pragma unroll
  for (int j = 0; j < 32; j += 8)
    dst[(size_t)(n0 + ty + j) * 2048 + (k0 + tx)] = f2bf(s[tx][ty + j]);
}

// ---- fused QKV projection: X[16384][2048] @ WqkvT[3072][2048]^T ----
__global__ void __launch_bounds__(256, 4) k_proj_qkv(const u16* __restrict__ X,
                                                     const u16* __restrict__ Wt,
                                                     const float* __restrict__ bq,
                                                     const float* __restrict__ bk,
                                                     const float* __restrict__ bv,
                                                     u16* __restrict__ Qb,
                                                     u16* __restrict__ Kb,
                                                     u16* __restrict__ Vt) {
  __shared__ __align__(16) u16 sA[2 * 4096];
  __shared__ __align__(16) u16 sB[2 * 4096];
  int tile = xcd_swz(blockIdx.x, 3072);
  int bm = tile / 24, bn = tile - bm * 24;   // row-major (A-panel resident)
  floatx4 acc[4][4];
  gemm128_core(X, K2, Wt, K2, bm * 128, bn * 128, K2, sA, sB, acc);

  const int t = threadIdx.x, w = t >> 6, l = t & 63;
  const int wr = w >> 1, wc = w & 1;
  const int r0 = bm * 128 + wr * 64 + ((l >> 4) << 2);
  const int c0 = (bn & 7) * 128 + wc * 64 + (l & 15);
  const int which = bn >> 3;  // 0:Q 1:K 2:V
  if (which == 2) {
#pragma unroll
    for (int ni = 0; ni < 4; ni++) {
      int h = c0 + ni * 16;
      float bvv = bv[h];
#pragma unroll
      for (int mi = 0; mi < 4; mi++) {
        int rg = r0 + mi * 16;                 // %4==0, no batch crossing
        int b = rg >> 11, n = rg & 2047;
        ushort4 o = { f2bf(acc[mi][ni][0] + bvv), f2bf(acc[mi][ni][1] + bvv),
                      f2bf(acc[mi][ni][2] + bvv), f2bf(acc[mi][ni][3] + bvv) };
        *(ushort4*)&Vt[((size_t)b * 1024 + h) * 2048 + n] = o;
      }
    }
  } else {
    u16* Out = (which == 0) ? Qb : Kb;
    const float* bias = (which == 0) ? bq : bk;
#pragma unroll
    for (int ni = 0; ni < 4; ni++) {
      int c1 = c0 + ni * 16;
      float bvv = bias[c1];
#pragma unroll
      for (int mi = 0; mi < 4; mi++)
#pragma unroll
        for (int i = 0; i < 4; i++)
          Out[(size_t)(r0 + mi * 16 + i) * 1024 + c1] = f2bf(acc[mi][ni][i] + bvv);
    }
  }
}

// ---- scores: E = exp(Q.K^T/32) bf16, row sums via atomics ----
__global__ void __launch_bounds__(256, 4) k_scores(const u16* __restrict__ Q, const u16* __restrict__ Kb,
                                                   u16* __restrict__ E, float* __restrict__ lsum) {
  __shared__ __align__(16) u16 sA[2 * 4096];
  __shared__ __align__(16) u16 sB[2 * 4096];
  int tile = xcd_swz(blockIdx.x, 2048);
  int b = tile >> 8, r = tile & 255, bm = r >> 4, bn = r & 15;
  const u16* A = Q + (size_t)b * NN * HH;
  const u16* Bt = Kb + (size_t)b * NN * HH;
  floatx4 acc[4][4];
  gemm128_core(A, HH, Bt, HH, bm * 128, bn * 128, HH, sA, sB, acc);

  u16* Eb = E + (size_t)b * NN * NN;
  float* lb = lsum + b * NN;
  const int t = threadIdx.x, w = t >> 6, l = t & 63;
  const int wr = w >> 1, wc = w & 1;
  const int q0 = bm * 128 + wr * 64 + ((l >> 4) << 2);
  const int k0c = bn * 128 + wc * 64 + (l & 15);
#pragma unroll
  for (int mi = 0; mi < 4; mi++)
#pragma unroll
    for (int i = 0; i < 4; i++) {
      int q = q0 + mi * 16 + i;
      float rs = 0.f;
#pragma unroll
      for (int ni = 0; ni < 4; ni++) {
        float e = expf(acc[mi][ni][i] * 0.03125f);
        Eb[(size_t)q * NN + k0c + ni * 16] = f2bf(e);
        rs += e;
      }
      rs += __shfl_xor(rs, 1);
      rs += __shfl_xor(rs, 2);
      rs += __shfl_xor(rs, 4);
      rs += __shfl_xor(rs, 8);
      if ((l & 15) == 0) atomicAdd(&lb[q], rs);
    }
}

// ---- PV: out = (gate/l).(E @ V) + sem, f32 ----
__global__ void __launch_bounds__(256, 4) k_pv(const u16* __restrict__ E, const u16* __restrict__ Vt,
                                               const float* __restrict__ gate, const float* __restrict__ lsum,
                                               const float* __restrict__ sem, float* __restrict__ out) {
  __shared__ __align__(16) u16 sA[2 * 4096];
  __shared__ __align__(16) u16 sB[2 * 4096];
  int tile = xcd_swz(blockIdx.x, 1024);
  int b = tile >> 7, r = tile & 127, bm = r >> 3, bn = r & 7;
  const u16* A = E + (size_t)b * NN * NN;
  const u16* Bt = Vt + (size_t)b * HH * NN;
  floatx4 acc[4][4];
  gemm128_core(A, NN, Bt, NN, bm * 128, bn * 128, NN, sA, sB, acc);

  const int t = threadIdx.x, w = t >> 6, l = t & 63;
  const int wr = w >> 1, wc = w & 1;
  const int q0 = bm * 128 + wr * 64 + ((l >> 4) << 2);
  const int h0 = bn * 128 + wc * 64 + (l & 15);
#pragma unroll
  for (int mi = 0; mi < 4; mi++)
#pragma unroll
    for (int i = 0; i < 4; i++) {
      int q = q0 + mi * 16 + i;
      size_t gq = (size_t)b * NN + q;
      float wq = gate[gq] / lsum[gq];
#pragma unroll
      for (int ni = 0; ni < 4; ni++) {
        int h = h0 + ni * 16;
        out[gq * HH + h] = acc[mi][ni][i] * wq + sem[gq * HH + h];
      }
    }
}

// ---- column mean (coalesced): cm[b][k] = (1/N) sum_q (gate/l)_q E[b][q][k] ----
__global__ void __launch_bounds__(256) k_colmean(const u16* __restrict__ E, const float* __restrict__ gate,
                                                 const float* __restrict__ lsum, float* __restrict__ cm) {
  __shared__ float wsh[256];
  int bid = blockIdx.x;           // 8 b x 4 kslice x 8 qchunk
  int b = bid >> 5, rest = bid & 31;
  int ks = rest >> 3, qc = rest & 7;
  int t = threadIdx.x;
  {
    size_t gq = (size_t)b * NN + qc * 256 + t;
    wsh[t] = gate[gq] / lsum[gq];
  }
  __syncthreads();
  const u16* Eb = E + ((size_t)b * NN + (size_t)qc * 256) * NN + ks * 512 + 2 * t;
  float s0 = 0.f, s1 = 0.f;
#pragma unroll 4
  for (int q = 0; q < 256; q++) {
    unsigned v = *(const unsigned*)(Eb + (size_t)q * NN);
    float wq = wsh[q];
    s0 += wq * __uint_as_float(v << 16);
    s1 += wq * __uint_as_float(v & 0xffff0000u);
  }
  float* c = cm + b * NN + ks * 512 + 2 * t;
  atomicAdd(c, s0 * (1.f / 2048.f));
  atomicAdd(c + 1, s1 * (1.f / 2048.f));
}

extern "C" void kernel_launch(void* const* d_in, const int* in_sizes, int n_in,
                              void* d_out, int out_size, void* d_ws, size_t ws_size,
                              hipStream_t stream) {
  const float* sem  = (const float*)d_in[0];
  const float* temp = (const float*)d_in[1];
  const float* Wq   = (const float*)d_in[2];
  const float* bq   = (const float*)d_in[3];
  const float* Wk   = (const float*)d_in[4];
  const float* bk   = (const float*)d_in[5];
  const float* Wv   = (const float*)d_in[6];
  const float* bv   = (const float*)d_in[7];
  const float* Wg   = (const float*)d_in[8];
  const float* bg   = (const float*)d_in[9];
  float* out = (float*)d_out;

  char* ws = (char*)d_ws;
  u16* X      = (u16*)ws;                      // 67,108,864 B (reused as E later)
  u16* E      = X;
  u16* WqkvT  = (u16*)(ws + 67108864);         // 3072x2048 bf16 = 12,582,912 B
  u16* Qb     = (u16*)(ws + 79691776);         // 33,554,432 B each
  u16* Kb     = (u16*)(ws + 113246208);
  u16* Vt     = (u16*)(ws + 146800640);
  float* gate = (float*)(ws + 180355072);      // 65,536 B
  float* lsum = (float*)(ws + 180420608);      // 65,536 B

  hipMemsetAsync(lsum, 0, 65536, stream);
  hipMemsetAsync(out + 16777216, 0, 65536, stream);  // colmean region of d_out

  k_prep_gate<<<2048, 256, 0, stream>>>(sem, temp, Wg, bg, X, gate);
  k_transpose_w3<<<6144, 256, 0, stream>>>(Wq, Wk, Wv, WqkvT);
  k_proj_qkv<<<3072, 256, 0, stream>>>(X, WqkvT, bq, bk, bv, Qb, Kb, Vt);
  k_scores<<<2048, 256, 0, stream>>>(Qb, Kb, E, lsum);   // overwrites X with E (X dead now)
  k_pv<<<1024, 256, 0, stream>>>(E, Vt, gate, lsum, sem, out);
  k_colmean<<<256, 256, 0, stream>>>(E, gate, lsum, out + 16777216);
}